// Round 1
// baseline (96.793 us; speedup 1.0000x reference)
//
#include <hip/hip_runtime.h>

// NCC loss: 9x9 box-filtered local cross-correlation, -mean(cc).
// Inputs: y_pred, y_true (32,4,512,512) fp32. Output: scalar fp32.

#define PAD 4
#define EPS 1e-5f

constexpr int B = 32, C = 4, H = 512, W = 512;
constexpr int ROWS = 32;           // output rows per block
constexpr int TPB = 128;           // threads per block (2 waves)
constexpr int CPT = 4;             // columns per thread (128*4 = 512 = W)
constexpr int SLOTS = 528;         // 512 + 2*PAD halo, padded to x16B
constexpr int NCHUNK = H / ROWS;   // 16
constexpr int NBLK = B * C * NCHUNK;  // 2048
constexpr float INV_N = 1.0f / 81.0f;

template <bool ADD>
__device__ __forceinline__ void accrow(const float* __restrict__ I,
                                       const float* __restrict__ J,
                                       int r, int x0,
                                       float sI[CPT], float sJ[CPT],
                                       float sI2[CPT], float sJ2[CPT],
                                       float sIJ[CPT]) {
    const float4 vi = *(const float4*)(I + (size_t)r * W + x0);
    const float4 vj = *(const float4*)(J + (size_t)r * W + x0);
    float fi[CPT] = {vi.x, vi.y, vi.z, vi.w};
    float fj[CPT] = {vj.x, vj.y, vj.z, vj.w};
#pragma unroll
    for (int k = 0; k < CPT; ++k) {
        float a = fi[k], b = fj[k];
        if (ADD) {
            sI[k] += a; sJ[k] += b;
            sI2[k] += a * a; sJ2[k] += b * b; sIJ[k] += a * b;
        } else {
            sI[k] -= a; sJ[k] -= b;
            sI2[k] -= a * a; sJ2[k] -= b * b; sIJ[k] -= a * b;
        }
    }
}

__global__ __launch_bounds__(TPB) void ncc_partial(
        const float* __restrict__ y_pred, const float* __restrict__ y_true,
        float* __restrict__ partial) {
    __shared__ float vs[5][SLOTS];
    __shared__ float wsum[TPB / 64];

    const int bid = blockIdx.x;
    const int chunk = bid % NCHUNK;
    const int plane = bid / NCHUNK;
    const size_t base = (size_t)plane * H * W;
    const float* I = y_true + base;  // reference: I = y_true
    const float* J = y_pred + base;  // reference: J = y_pred

    const int t = threadIdx.x;
    const int x0 = t * CPT;  // this thread's 4 output columns

    // Zero the halo slots once (SAME zero-padding); never rewritten.
    if (t < 2 * PAD) {
        int s = (t < PAD) ? t : (512 + t);  // slots 0..3 and 516..519
#pragma unroll
        for (int ch = 0; ch < 5; ++ch) vs[ch][s] = 0.0f;
    }

    const int y0 = chunk * ROWS;

    // Running vertical sums over rows [y-4, y+4] for 5 moment channels.
    float sI[CPT] = {0.f, 0.f, 0.f, 0.f}, sJ[CPT] = {0.f, 0.f, 0.f, 0.f};
    float sI2[CPT] = {0.f, 0.f, 0.f, 0.f}, sJ2[CPT] = {0.f, 0.f, 0.f, 0.f};
    float sIJ[CPT] = {0.f, 0.f, 0.f, 0.f};

    // Prime with rows [y0-4, y0+3] ∩ [0,H)
    for (int r = y0 - PAD; r < y0 + PAD; ++r) {
        if (r >= 0 && r < H)
            accrow<true>(I, J, r, x0, sI, sJ, sI2, sJ2, sIJ);
    }

    float acc = 0.0f;

    for (int yo = 0; yo < ROWS; ++yo) {
        const int y = y0 + yo;
        const int rin = y + PAD;
        if (rin < H) accrow<true>(I, J, rin, x0, sI, sJ, sI2, sJ2, sIJ);
        // vsums now cover rows [y-4, y+4] (zero outside image)

        __syncthreads();  // previous iteration's LDS reads complete
        *(float4*)&vs[0][x0 + PAD] = make_float4(sI[0], sI[1], sI[2], sI[3]);
        *(float4*)&vs[1][x0 + PAD] = make_float4(sJ[0], sJ[1], sJ[2], sJ[3]);
        *(float4*)&vs[2][x0 + PAD] = make_float4(sI2[0], sI2[1], sI2[2], sI2[3]);
        *(float4*)&vs[3][x0 + PAD] = make_float4(sJ2[0], sJ2[1], sJ2[2], sJ2[3]);
        *(float4*)&vs[4][x0 + PAD] = make_float4(sIJ[0], sIJ[1], sIJ[2], sIJ[3]);
        __syncthreads();

        // Horizontal 9-sum: window for output x0+k is slots [x0+k, x0+k+8].
        float h[5][CPT];
#pragma unroll
        for (int ch = 0; ch < 5; ++ch) {
            const float* row = vs[ch];
            const float4 a = *(const float4*)(row + x0);
            const float4 b = *(const float4*)(row + x0 + 4);
            const float4 c = *(const float4*)(row + x0 + 8);
            float s = a.x + a.y + a.z + a.w + b.x + b.y + b.z + b.w + c.x;
            h[ch][0] = s;
            s += c.y - a.x; h[ch][1] = s;
            s += c.z - a.y; h[ch][2] = s;
            s += c.w - a.z; h[ch][3] = s;
        }

#pragma unroll
        for (int k = 0; k < CPT; ++k) {
            const float mI = h[0][k] * INV_N;
            const float mJ = h[1][k] * INV_N;
            const float vI = h[2][k] * INV_N - mI * mI;
            const float vJ = h[3][k] * INV_N - mJ * mJ;
            const float cv = h[4][k] * INV_N - mI * mJ;
            const float den = fmaxf(vI, 0.0f) * fmaxf(vJ, 0.0f) + EPS;
            acc += cv * cv / den;
        }

        const int rout = y - PAD;
        if (rout >= 0) accrow<false>(I, J, rout, x0, sI, sJ, sI2, sJ2, sIJ);
    }

    // Block reduction (deterministic): wave shuffle + LDS
#pragma unroll
    for (int off = 32; off > 0; off >>= 1)
        acc += __shfl_down(acc, off, 64);
    __syncthreads();  // vs reads all done (wsum shares LDS space lifetime)
    if ((t & 63) == 0) wsum[t >> 6] = acc;
    __syncthreads();
    if (t == 0) partial[bid] = wsum[0] + wsum[1];
}

__global__ __launch_bounds__(256) void ncc_final(
        const float* __restrict__ partial, float* __restrict__ out) {
    const int t = threadIdx.x;
    float s = 0.0f;
    for (int i = t; i < NBLK; i += 256) s += partial[i];
    __shared__ float ws[4];
#pragma unroll
    for (int off = 32; off > 0; off >>= 1)
        s += __shfl_down(s, off, 64);
    if ((t & 63) == 0) ws[t >> 6] = s;
    __syncthreads();
    if (t == 0) {
        const float tot = ws[0] + ws[1] + ws[2] + ws[3];
        out[0] = -tot / (float)((long long)B * C * H * W);
    }
}

extern "C" void kernel_launch(void* const* d_in, const int* in_sizes, int n_in,
                              void* d_out, int out_size, void* d_ws, size_t ws_size,
                              hipStream_t stream) {
    const float* y_pred = (const float*)d_in[0];
    const float* y_true = (const float*)d_in[1];
    float* out = (float*)d_out;
    float* partial = (float*)d_ws;  // NBLK floats = 8 KB

    ncc_partial<<<NBLK, TPB, 0, stream>>>(y_pred, y_true, partial);
    ncc_final<<<1, 256, 0, stream>>>(partial, out);
}